// Round 1
// baseline (31923.849 us; speedup 1.0000x reference)
//
#include <hip/hip_runtime.h>
#include <hip/hip_bf16.h>
#include <stdint.h>

// LSTM: B=32, T=2048, I=256, H=512. torch gate order i,f,g,o.
// Single persistent kernel, 32 blocks x 512 threads. Cross-block h exchange:
// bf16 pair + step tag packed in ONE 64-bit agent-scope relaxed atomic word;
// two-slot ping-pong makes exact tag match ABA-safe.
//
// R1 changes vs 7136us baseline:
//  (a) __launch_bounds__(512,2): only 8 waves/CU ever reside (1 block/CU), so
//      256 VGPR/wave is free. At the old 124-reg cap the 96-reg weight file
//      forced the 16-word poll into serialized LLC round-trip chunks.
//  (b) waves remapped (m-tile, gate) -> (m-tile, K-chunk): one Als A-fragment
//      read feeds 4 MFMAs (all gates). LDS A-read traffic 196KB -> 48KB per
//      CU-step; acc dep-chain 24 -> 6. K-partials reduced via ds_add_f32 into
//      a DOUBLE-BUFFERED gate accumulator (single-buffer zeroing pre-bar1
//      would race a slow wave's epilogue reads of the previous step).
//  (c) poll first pass issued immediately; x convert + g_ls zero overlap the
//      load flight.
//  (d) init poisons slot 1: kills a cross-replay stale tag-2047 ABA race.

#define B_   32
#define T_   2048
#define I_   256
#define H_   512
#define NB   32          // recurrent blocks (one per 16 h-columns)
#define NTHR 512         // 8 waves
#define JC   16          // h-columns per block = H_/NB
#define SA   776         // padded LDS stride (multiple of 8 -> 16B-aligned rows)
#define KSL  6           // K-steps per K-chunk: 4 chunks * 6 * 32 = 768 = H+I
#define NPAIR (B_ * H_ / 2)   // 8192 u64 words per slot

typedef __attribute__((ext_vector_type(8))) short short8;
typedef __attribute__((ext_vector_type(4))) float f32x4;

__device__ __forceinline__ unsigned short f2bf_bits(float v) {
    unsigned int u = __builtin_bit_cast(unsigned int, v);
    unsigned int r = (u + 0x7FFFu + ((u >> 16) & 1u)) >> 16;   // RNE
    return (unsigned short)r;
}
__device__ __forceinline__ float sigm(float x) {
    return 1.0f / (1.0f + __expf(-x));
}
__device__ __forceinline__ float tanh_fast(float x) {
    float e = __expf(2.0f * x);          // inf-safe: e=inf -> 1; e=0 -> -1
    return 1.0f - 2.0f / (e + 1.0f);
}

// Slot 0: (tag=0, h0 pairs). Slot 1: explicit poison tag (never matches any t;
// also removes the cross-replay stale tag-2047 match).
__global__ void lstm_init(const float* __restrict__ h0,
                          unsigned long long* __restrict__ hbuf) {
    int i = blockIdx.x * 256 + threadIdx.x;   // pair index 0..NPAIR-1
    if (i < NPAIR) {
        const int b = i >> 8;                 // 256 pairs per batch row
        const int c = (i & 255) * 2;
        const unsigned lo = f2bf_bits(h0[b * H_ + c]);
        const unsigned hi = f2bf_bits(h0[b * H_ + c + 1]);
        const unsigned pair = lo | (hi << 16);
        hbuf[i] = ((unsigned long long)pair << 32) | 0u;   // tag 0
        hbuf[NPAIR + i] = 0xFFFFFFFFull;                   // poison slot 1
    }
}

__global__ __launch_bounds__(NTHR, 2) void lstm_persistent(
    const float* __restrict__ x,    // [B,T,I]
    const float* __restrict__ c0,   // [1,B,H]
    const float* __restrict__ Wih,  // [4H,I]
    const float* __restrict__ Whh,  // [4H,H]
    const float* __restrict__ bih,  // [4H]
    const float* __restrict__ bhh,  // [4H]
    float* __restrict__ out,        // result [B,T,H] ++ h_f [B,H] ++ c_f [B,H]
    unsigned long long* hbuf)       // [2][NPAIR] (tag | bf16-pair<<32)
{
    __shared__ __align__(16) unsigned short Als[B_][SA];  // A tile: [m][k] h|x
    __shared__ float g_ls[2][B_][4 * JC + 4];  // gate preacts, double-buffered

    const int tid  = threadIdx.x;
    const int bid  = blockIdx.x;
    const int lane = tid & 63;
    const int wave = tid >> 6;          // 0..7
    const int ks   = wave & 3;          // K-chunk 0..3
    const int mi   = (wave >> 2) * 16;  // batch-tile base (0 or 16)
    const int l15  = lane & 15;
    const int kq8  = (lane >> 4) * 8;   // k sub-block within a 32-wide K step

    // ---- persistent B fragments: ALL 4 gates of this wave's K-chunk ----
    // B[k][n] = W[row(q,n)][k], n = l15. 4 gates x 6 steps x 4 VGPR = 96 regs.
    short8 bfrag[4][KSL];
#pragma unroll
    for (int q = 0; q < 4; ++q) {
        const int grow = q * H_ + bid * JC + l15;   // global gate row
#pragma unroll
        for (int s = 0; s < KSL; ++s) {
            const int k0 = ks * (KSL * 32) + s * 32 + kq8;
            short8 f;
#pragma unroll
            for (int j = 0; j < 8; ++j) {
                const int k = k0 + j;
                const float v = (k < H_) ? Whh[(size_t)grow * H_ + k]
                                         : Wih[(size_t)grow * I_ + (k - H_)];
                f[j] = (short)f2bf_bits(v);
            }
            bfrag[q][s] = f;
        }
    }

    // ---- per-thread epilogue state in registers ----
    const int eb   = tid >> 4;          // batch 0..31
    const int ejj  = tid & 15;          // column-in-block 0..15
    const int ecol = bid * JC + ejj;    // global h column
    float bias_i = bih[0 * H_ + ecol] + bhh[0 * H_ + ecol];
    float bias_f = bih[1 * H_ + ecol] + bhh[1 * H_ + ecol];
    float bias_g = bih[2 * H_ + ecol] + bhh[2 * H_ + ecol];
    float bias_o = bih[3 * H_ + ecol] + bhh[3 * H_ + ecol];
    float c_reg  = c0[eb * H_ + ecol];

    for (int t = 0; t < T_; ++t) {
        const unsigned tt = (unsigned)t;
        const int p = t & 1;

        // ---- issue x_t loads (HBM latency hides under the poll) ----
        float4 xv[4];
#pragma unroll
        for (int i = 0; i < 4; ++i) {
            const int idx = tid + i * NTHR;           // 0..2047 float4s
            const int m = idx >> 6, k4 = idx & 63;
            xv[i] = *(const float4*)(x + (size_t)m * T_ * I_ +
                                     (size_t)t * I_ + k4 * 4);
        }

        // ---- issue poll first pass: all 16 words in flight at once ----
        unsigned long long* hsrc = hbuf + (size_t)p * NPAIR;
        unsigned long long hv[16];
#pragma unroll
        for (int i = 0; i < 16; ++i) {
            hv[i] = __hip_atomic_load(&hsrc[tid + i * NTHR],
                                      __ATOMIC_RELAXED,
                                      __HIP_MEMORY_SCOPE_AGENT);
        }

        // ---- overlap the load flight: convert & write x to LDS ----
        // (Als writes safe pre-bar1: every wave passed bar2 of step t-1, and
        //  all step t-1 Als reads precede that barrier.)
#pragma unroll
        for (int i = 0; i < 4; ++i) {
            const int idx = tid + i * NTHR;
            const int m = idx >> 6, k4 = idx & 63;
            ushort4 pk;
            pk.x = f2bf_bits(xv[i].x); pk.y = f2bf_bits(xv[i].y);
            pk.z = f2bf_bits(xv[i].z); pk.w = f2bf_bits(xv[i].w);
            *(ushort4*)&Als[m][H_ + k4 * 4] = pk;
        }
        // ---- zero this step's gate accumulator (buffer p; its previous
        //      readers were epilogue(t-2), separated by bar1(t-1)) ----
        {
            float* gz = g_ls[p][eb];
            gz[ejj] = 0.f; gz[JC + ejj] = 0.f;
            gz[2 * JC + ejj] = 0.f; gz[3 * JC + ejj] = 0.f;
        }

        // ---- finish poll: exact tag match delivers the data ----
        unsigned need = 0;
#pragma unroll
        for (int i = 0; i < 16; ++i)
            if ((unsigned)hv[i] != tt) need |= (1u << i);
        while (need) {
#pragma unroll
            for (int i = 0; i < 16; ++i) {
                if (need & (1u << i)) {
                    hv[i] = __hip_atomic_load(&hsrc[tid + i * NTHR],
                                              __ATOMIC_RELAXED,
                                              __HIP_MEMORY_SCOPE_AGENT);
                }
            }
            unsigned ok = 0;
#pragma unroll
            for (int i = 0; i < 16; ++i)
                if ((unsigned)hv[i] == tt) ok |= (1u << i);
            need &= ~ok;
        }

        // ---- write h pairs to LDS ----
#pragma unroll
        for (int i = 0; i < 16; ++i) {
            const int j = tid + i * NTHR;             // pair index 0..NPAIR-1
            const int m = j >> 8;                     // 256 pairs per batch
            const int c = (j & 255) * 2;              // bf16 column
            *(unsigned int*)&Als[m][c] = (unsigned int)(hv[i] >> 32);
        }
        __syncthreads();                              // barrier #1

        // ---- partial gates over this wave's K-chunk: one A-read -> 4 MFMA ----
        f32x4 acc0 = {0.f, 0.f, 0.f, 0.f};
        f32x4 acc1 = acc0, acc2 = acc0, acc3 = acc0;
        const int mrow  = mi + l15;
        const int kbase = ks * (KSL * 32) + kq8;
#pragma unroll
        for (int s = 0; s < KSL; ++s) {
            const short8 a = *(const short8*)&Als[mrow][kbase + s * 32];
            acc0 = __builtin_amdgcn_mfma_f32_16x16x32_bf16(a, bfrag[0][s], acc0, 0, 0, 0);
            acc1 = __builtin_amdgcn_mfma_f32_16x16x32_bf16(a, bfrag[1][s], acc1, 0, 0, 0);
            acc2 = __builtin_amdgcn_mfma_f32_16x16x32_bf16(a, bfrag[2][s], acc2, 0, 0, 0);
            acc3 = __builtin_amdgcn_mfma_f32_16x16x32_bf16(a, bfrag[3][s], acc3, 0, 0, 0);
        }
        // ---- reduce the 4 K-chunk partials: ds_add_f32 into g_ls[p] ----
        {
            float (*gw)[4 * JC + 4] = g_ls[p];
            const int r0 = mi + (lane >> 4) * 4;      // D: col=lane&15, row=r0+r
#pragma unroll
            for (int r = 0; r < 4; ++r) {
                atomicAdd(&gw[r0 + r][0 * JC + l15], acc0[r]);
                atomicAdd(&gw[r0 + r][1 * JC + l15], acc1[r]);
                atomicAdd(&gw[r0 + r][2 * JC + l15], acc2[r]);
                atomicAdd(&gw[r0 + r][3 * JC + l15], acc3[r]);
            }
        }
        __syncthreads();                              // barrier #2

        // ---- epilogue: one thread per (batch, column) ----
        const float* ge = g_ls[p][eb];
        const float pi = ge[ejj]          + bias_i;
        const float pf = ge[JC + ejj]     + bias_f;
        const float pg = ge[2 * JC + ejj] + bias_g;
        const float po = ge[3 * JC + ejj] + bias_o;
        const float ig = sigm(pi), fg = sigm(pf);
        const float gg = tanh_fast(pg), og = sigm(po);
        c_reg = fg * c_reg + ig * gg;
        const float h = og * tanh_fast(c_reg);

        // ---- publish h(t+1): fire-and-forget tagged u64 ----
        const unsigned hvb = f2bf_bits(h);
        const unsigned nbv = __shfl_xor(hvb, 1);
        if ((ejj & 1) == 0) {
            const unsigned pair = hvb | (nbv << 16);
            const unsigned long long word =
                ((unsigned long long)pair << 32) | (unsigned)(t + 1);
            __hip_atomic_store(
                &hbuf[(size_t)((t + 1) & 1) * NPAIR + eb * 256 + (ecol >> 1)],
                word, __ATOMIC_RELAXED, __HIP_MEMORY_SCOPE_AGENT);
        }

        // ---- deferred HBM stores (off the recurrence critical path) ----
        out[(size_t)eb * T_ * H_ + (size_t)t * H_ + ecol] = h;
        if (t == T_ - 1) {
            out[(size_t)B_ * T_ * H_ + eb * H_ + ecol] = h;               // h_f
            out[(size_t)B_ * T_ * H_ + B_ * H_ + eb * H_ + ecol] = c_reg; // c_f
        }
        // No third barrier: next iteration's Als/g_ls writes are ordered
        // against this step's readers by bar1/bar2 (g_ls via double-buffer:
        // buffer p's previous readers were epilogue(t-2), before bar1(t-1)).
    }
}

extern "C" void kernel_launch(void* const* d_in, const int* in_sizes, int n_in,
                              void* d_out, int out_size, void* d_ws, size_t ws_size,
                              hipStream_t stream) {
    const float* x   = (const float*)d_in[0];
    const float* h0  = (const float*)d_in[1];
    const float* c0  = (const float*)d_in[2];
    const float* Wih = (const float*)d_in[3];
    const float* Whh = (const float*)d_in[4];
    const float* bih = (const float*)d_in[5];
    const float* bhh = (const float*)d_in[6];
    float* out = (float*)d_out;

    unsigned long long* hbuf = (unsigned long long*)d_ws;   // 2*8192*8 = 128 KB

    hipLaunchKernelGGL(lstm_init, dim3(32), dim3(256), 0, stream, h0, hbuf);
    hipLaunchKernelGGL(lstm_persistent, dim3(NB), dim3(NTHR), 0, stream,
                       x, c0, Wih, Whh, bih, bhh, out, hbuf);
}

// Round 3
// 10424.352 us; speedup vs baseline: 3.0624x; 3.0624x over previous
//
#include <hip/hip_runtime.h>
#include <hip/hip_bf16.h>
#include <stdint.h>

// LSTM: B=32, T=2048, I=256, H=512. torch gate order i,f,g,o.
// R3 = R0's proven dataflow + exchange (agent-scope LLC atomics, row-major
// hbuf, 32 blocks x 512 threads) with three safe upgrades:
//  (1) __launch_bounds__(512,1): R1 evidence shows the 2nd arg is CUDA-style
//      blocks/CU; (512,1) -> 256-VGPR cap. R0's 124-reg cap couldn't keep
//      bfrag(96)+poll(32)+xv(16) live -> poll was chunked into serialized
//      LLC round trips. ~180 live regs now, no spill.
//  (2) x-GEMM (8 of 24 MFMAs, no h dependence) runs BETWEEN poll-issue and
//      poll-check -> hides part of the publish->poll LLC latency. x is
//      pipelined two steps ahead through a double-buffered Axls so no
//      __syncthreads (which drains vmcnt!) sits between issue and check.
//  (3) Als/Axls: pow-2 row strides + ((row&7)) XOR on 16B slots, write and
//      read sides consistent -> R0's 5.9e7 conflict cycles (~900cy/CU/step,
//      inside the barrier-bracketed GEMM phase) -> ~2-way (free).
// R2's one-XCD election + L2 exchange is shelved: it stacked two unverified
// cache-semantics assumptions and hung.

#define B_   32
#define T_   2048
#define I_   256
#define H_   512
#define NB   32          // recurrent blocks (one per 16 h-columns)
#define NTHR 512         // 8 waves
#define JC   16          // h-columns per block = H_/NB
#define KSTEPS 24        // (H_+I_)/32
#define NPAIR (B_ * H_ / 2)   // 8192 u64 words per slot

typedef __attribute__((ext_vector_type(8))) short short8;
typedef __attribute__((ext_vector_type(4))) float f32x4;

__device__ __forceinline__ unsigned short f2bf_bits(float v) {
    unsigned int u = __builtin_bit_cast(unsigned int, v);
    unsigned int r = (u + 0x7FFFu + ((u >> 16) & 1u)) >> 16;   // RNE
    return (unsigned short)r;
}
__device__ __forceinline__ float sigm(float x) {
    return 1.0f / (1.0f + __expf(-x));
}
__device__ __forceinline__ float tanh_fast(float x) {
    float e = __expf(2.0f * x);          // inf-safe: e=inf -> 1; e=0 -> -1
    return 1.0f - 2.0f / (e + 1.0f);
}

// hbuf word w: b = w>>8, bf16 cols (w&255)*2 .. +1. word = (pair<<32)|tag.
// Slot 0 gets (tag=0, h0); slot 1 poisoned (tag 0xFFFFFFFF never matches).
__global__ void lstm_init(const float* __restrict__ h0,
                          unsigned long long* __restrict__ hbuf) {
    int i = blockIdx.x * 256 + threadIdx.x;   // word index 0..NPAIR-1
    if (i < NPAIR) {
        const int b = i >> 8;                 // 256 pairs per batch row
        const int c = (i & 255) * 2;
        const unsigned lo = f2bf_bits(h0[b * H_ + c]);
        const unsigned hi = f2bf_bits(h0[b * H_ + c + 1]);
        const unsigned pair = lo | (hi << 16);
        hbuf[i] = ((unsigned long long)pair << 32) | 0u;   // tag 0
        hbuf[NPAIR + i] = 0xFFFFFFFFull;                   // poison slot 1
    }
}

__global__ __launch_bounds__(NTHR, 1) void lstm_persistent(
    const float* __restrict__ x,    // [B,T,I]
    const float* __restrict__ c0,   // [1,B,H]
    const float* __restrict__ Wih,  // [4H,I]
    const float* __restrict__ Whh,  // [4H,H]
    const float* __restrict__ bih,  // [4H]
    const float* __restrict__ bhh,  // [4H]
    float* __restrict__ out,        // result [B,T,H] ++ h_f [B,H] ++ c_f [B,H]
    unsigned long long* hbuf)       // [2][NPAIR] (tag | bf16-pair<<32)
{
    // h tile: [32][512] bf16, 1024B rows; 16B-slot index XOR (row&7).
    __shared__ __align__(16) unsigned short Als[B_][512];      // 32 KB
    // x tile: [2][32][256] bf16, 512B rows, same swizzle; double-buffered
    // so x(t+1) staging never needs a barrier adjacent to the poll.
    __shared__ __align__(16) unsigned short Axls[2][B_][256];  // 32 KB
    __shared__ float g_ls[B_][4 * JC + 1];

    const int tid  = threadIdx.x;
    const int bid  = blockIdx.x;
    const int lane = tid & 63;
    const int wave = tid >> 6;          // 0..7
    const int mi   = (wave & 1) * 16;   // batch-tile base (0 or 16)
    const int q    = wave >> 1;         // gate index 0..3 == n-tile
    const int l15  = lane & 15;
    const int kq8  = (lane >> 4) * 8;   // k sub-block within a 32-wide K step
    const int qv   = lane >> 4;         // 16B-slot sub-index within a K step

    // ---- persistent B fragments: B[k][n] = W[row(n)][k], n = l15 ----
    const int grow = q * H_ + bid * JC + l15;   // global gate row
    short8 bfrag[KSTEPS];
#pragma unroll
    for (int s = 0; s < KSTEPS; ++s) {
        const int k0 = s * 32 + kq8;
        short8 f;
#pragma unroll
        for (int j = 0; j < 8; ++j) {
            const int k = k0 + j;
            const float v = (k < H_) ? Whh[(size_t)grow * H_ + k]
                                     : Wih[(size_t)grow * I_ + (k - H_)];
            f[j] = (short)f2bf_bits(v);
        }
        bfrag[s] = f;
    }

    // ---- per-thread epilogue state in registers ----
    const int eb   = tid >> 4;          // batch 0..31
    const int ejj  = tid & 15;          // column-in-block 0..15
    const int ecol = bid * JC + ejj;    // global h column
    float bias_i = bih[0 * H_ + ecol] + bhh[0 * H_ + ecol];
    float bias_f = bih[1 * H_ + ecol] + bhh[1 * H_ + ecol];
    float bias_g = bih[2 * H_ + ecol] + bhh[2 * H_ + ecol];
    float bias_o = bih[3 * H_ + ecol] + bhh[3 * H_ + ecol];
    float c_reg  = c0[eb * H_ + ecol];

    char* alsb = (char*)&Als[0][0];

    // ---- prologue: x(0) -> Axls[0]; issue x(1) into xv ----
    float4 xv[4];
#pragma unroll
    for (int i = 0; i < 4; ++i) {
        const int idx = tid + i * NTHR;
        const int m = idx >> 6, k4 = idx & 63;
        xv[i] = *(const float4*)(x + (size_t)m * T_ * I_ + k4 * 4);
    }
    {
        char* axw = (char*)&Axls[0][0][0];
#pragma unroll
        for (int i = 0; i < 4; ++i) {
            const int idx = tid + i * NTHR;
            const int m = idx >> 6, k4 = idx & 63;
            ushort4 pk;
            pk.x = f2bf_bits(xv[i].x); pk.y = f2bf_bits(xv[i].y);
            pk.z = f2bf_bits(xv[i].z); pk.w = f2bf_bits(xv[i].w);
            const unsigned a = (unsigned)(m * 512) +
                (((unsigned)(k4 >> 1) ^ (unsigned)(m & 7)) << 4) +
                (unsigned)((k4 & 1) * 8);
            *(ushort4*)(axw + a) = pk;
        }
    }
#pragma unroll
    for (int i = 0; i < 4; ++i) {       // issue x(1)
        const int idx = tid + i * NTHR;
        const int m = idx >> 6, k4 = idx & 63;
        xv[i] = *(const float4*)(x + (size_t)m * T_ * I_ + (size_t)I_ + k4 * 4);
    }
    __syncthreads();    // Axls[0] visible to all waves

    const int  mrow = mi + l15;
    const unsigned r7 = (unsigned)(mrow & 7);

    for (int t = 0; t < T_; ++t) {
        const unsigned tt = (unsigned)t;
        unsigned long long* hsrc = hbuf + (size_t)(t & 1) * NPAIR;

        // ---- P1: issue poll loads for h(t) (all 16 in flight) ----
        unsigned long long hv[16];
#pragma unroll
        for (int i = 0; i < 16; ++i) {
            hv[i] = __hip_atomic_load(&hsrc[tid + i * NTHR],
                                      __ATOMIC_RELAXED,
                                      __HIP_MEMORY_SCOPE_AGENT);
        }
        asm volatile("" ::: "memory");   // keep issue above the x-GEMM reads

        // ---- P2: x-GEMM (no h dependence) hides poll latency ----
        f32x4 acc = {0.f, 0.f, 0.f, 0.f};
        {
            const char* axb = (const char*)&Axls[t & 1][0][0];
#pragma unroll
            for (int s = 0; s < 8; ++s) {
                const unsigned off = (unsigned)(mrow * 512) +
                    (((unsigned)(s * 4 + qv) ^ r7) << 4);
                const short8 a = *(const short8*)(axb + off);
                acc = __builtin_amdgcn_mfma_f32_16x16x32_bf16(a, bfrag[16 + s], acc, 0, 0, 0);
            }
        }

        // ---- P3: finish poll (exact tag match delivers the data) ----
        unsigned need = 0;
#pragma unroll
        for (int i = 0; i < 16; ++i)
            if ((unsigned)hv[i] != tt) need |= (1u << i);
        while (need) {
#pragma unroll
            for (int i = 0; i < 16; ++i) {
                if (need & (1u << i)) {
                    hv[i] = __hip_atomic_load(&hsrc[tid + i * NTHR],
                                              __ATOMIC_RELAXED,
                                              __HIP_MEMORY_SCOPE_AGENT);
                }
            }
            unsigned ok = 0;
#pragma unroll
            for (int i = 0; i < 16; ++i)
                if ((unsigned)hv[i] == tt) ok |= (1u << i);
            need &= ~ok;
        }

        // ---- P4: write h pairs to LDS (swizzled) ----
#pragma unroll
        for (int i = 0; i < 16; ++i) {
            const int j  = tid + i * NTHR;            // word index
            const int m  = j >> 8;                    // batch row
            const int cp = j & 255;                   // pair column
            const unsigned a = (unsigned)(m * 1024) +
                (((unsigned)(cp >> 2) ^ (unsigned)(m & 7)) << 4) +
                (unsigned)((cp & 3) * 4);
            *(unsigned*)(alsb + a) = (unsigned)(hv[i] >> 32);
        }
        __syncthreads();                              // barrier #1

        // ---- P6: h-GEMM ----
#pragma unroll
        for (int s = 0; s < 16; ++s) {
            const unsigned off = (unsigned)(mrow * 1024) +
                (((unsigned)(s * 4 + qv) ^ r7) << 4);
            const short8 a = *(const short8*)(alsb + off);
            acc = __builtin_amdgcn_mfma_f32_16x16x32_bf16(a, bfrag[s], acc, 0, 0, 0);
        }
#pragma unroll
        for (int r = 0; r < 4; ++r) {                 // D: col=lane&15, row=(lane>>4)*4+r
            g_ls[mi + (lane >> 4) * 4 + r][q * JC + l15] = acc[r];
        }

        // ---- P7: stage x(t+1) into Axls[(t+1)&1] (safe: all waves past
        //      bar1(t) => all P2(t-1) reads of this buffer are done; next
        //      readers are at P2(t+1), past bar2(t)) ----
        {
            char* axw = (char*)&Axls[(t + 1) & 1][0][0];
#pragma unroll
            for (int i = 0; i < 4; ++i) {
                const int idx = tid + i * NTHR;
                const int m = idx >> 6, k4 = idx & 63;
                ushort4 pk;
                pk.x = f2bf_bits(xv[i].x); pk.y = f2bf_bits(xv[i].y);
                pk.z = f2bf_bits(xv[i].z); pk.w = f2bf_bits(xv[i].w);
                const unsigned a = (unsigned)(m * 512) +
                    (((unsigned)(k4 >> 1) ^ (unsigned)(m & 7)) << 4) +
                    (unsigned)((k4 & 1) * 8);
                *(ushort4*)(axw + a) = pk;
            }
        }
        __syncthreads();                              // barrier #2

        // ---- P9: epilogue (one thread per (batch, column)) ----
        const float pi = g_ls[eb][ejj]          + bias_i;
        const float pf = g_ls[eb][JC + ejj]     + bias_f;
        const float pg = g_ls[eb][2 * JC + ejj] + bias_g;
        const float po = g_ls[eb][3 * JC + ejj] + bias_o;
        const float ig = sigm(pi), fg = sigm(pf);
        const float gg = tanh_fast(pg), og = sigm(po);
        c_reg = fg * c_reg + ig * gg;
        const float h = og * tanh_fast(c_reg);

        // ---- publish h(t+1): fire-and-forget tagged u64 -> LLC ----
        const unsigned hvb = f2bf_bits(h);
        const unsigned nbv = __shfl_xor(hvb, 1);
        if ((ejj & 1) == 0) {
            const unsigned pair = hvb | (nbv << 16);
            const unsigned long long word =
                ((unsigned long long)pair << 32) | (unsigned)(t + 1);
            __hip_atomic_store(
                &hbuf[(size_t)((t + 1) & 1) * NPAIR + eb * 256 + (ecol >> 1)],
                word, __ATOMIC_RELAXED, __HIP_MEMORY_SCOPE_AGENT);
        }

        // ---- P10: issue x(t+2) loads (consumed at P7(t+1): ~a full step
        //      of latency cover) ----
        {
            const int tn = (t + 2 < T_) ? t + 2 : T_ - 1;
#pragma unroll
            for (int i = 0; i < 4; ++i) {
                const int idx = tid + i * NTHR;
                const int m = idx >> 6, k4 = idx & 63;
                xv[i] = *(const float4*)(x + (size_t)m * T_ * I_ +
                                         (size_t)tn * I_ + k4 * 4);
            }
        }

        // ---- P11: deferred HBM stores (off the recurrence critical path) ----
        out[(size_t)eb * T_ * H_ + (size_t)t * H_ + ecol] = h;
        if (t == T_ - 1) {
            out[(size_t)B_ * T_ * H_ + eb * H_ + ecol] = h;               // h_f
            out[(size_t)B_ * T_ * H_ + B_ * H_ + eb * H_ + ecol] = c_reg; // c_f
        }
        // No third barrier: Als writes (P4, t+1) follow bar2(t) in every
        // wave's program order; all P6(t) Als reads precede bar2(t). g_ls
        // reads (P9, t) precede bar1(t+1), writes (P6, t+1) follow it.
    }
}

extern "C" void kernel_launch(void* const* d_in, const int* in_sizes, int n_in,
                              void* d_out, int out_size, void* d_ws, size_t ws_size,
                              hipStream_t stream) {
    const float* x   = (const float*)d_in[0];
    const float* h0  = (const float*)d_in[1];
    const float* c0  = (const float*)d_in[2];
    const float* Wih = (const float*)d_in[3];
    const float* Whh = (const float*)d_in[4];
    const float* bih = (const float*)d_in[5];
    const float* bhh = (const float*)d_in[6];
    float* out = (float*)d_out;

    unsigned long long* hbuf = (unsigned long long*)d_ws;   // 2*8192*8 = 128 KB

    hipLaunchKernelGGL(lstm_init, dim3(32), dim3(256), 0, stream, h0, hbuf);
    hipLaunchKernelGGL(lstm_persistent, dim3(NB), dim3(NTHR), 0, stream,
                       x, c0, Wih, Whh, bih, bhh, out, hbuf);
}

// Round 6
// 7122.247 us; speedup vs baseline: 4.4823x; 1.4636x over previous
//
#include <hip/hip_runtime.h>
#include <hip/hip_bf16.h>
#include <stdint.h>

// LSTM: B=32, T=2048, I=256, H=512. torch gate order i,f,g,o.
// R6 == R5 resubmitted (R5 failed with a container-level error twice; audit
// found no kernel-side cause — the small-ws path is byte-identical to the
// thrice-proven R0 kernel, and the big path adds only stream-ordered
// launches with no novel sync. Suspect a node wedged by R4's flag-spin.
// Re-running unchanged keeps the experiment clean.)
//
// Design: hoist xg[t] = Wih * x_t out of the recurrence as TWO stream-ordered
// launches (no producer/consumer flags, no release fences, no co-residency
// assumptions).
//   phase 1: xg_gemm, 2048 blocks (one per t), bf16 MFMA, writes xg f32 slab.
//   phase 2: lstm_rec = R0's proven loop minus all x machinery:
//            16 MFMAs (was 24), no f2bf converts, no x staging; 4 xg floats
//            read per thread one step ahead. bfrag 96->64 regs frees the
//            poll's 32 regs under the 128-reg cap (R3 evidence).
// ws_size gated; too small -> byte-exact R0 fallback.
// R3 lessons kept: no swizzle (SQ_LDS_BANK_CONFLICT tracks b128 count, R0
// layout already bank-optimal); compiler caps at 128 VGPR regardless of
// launch_bounds, so shrink the live set instead of asking for regs.

#define B_   32
#define T_   2048
#define I_   256
#define H_   512
#define NB   32          // recurrent blocks
#define NTHR 512         // 8 waves
#define JC   16          // h-columns per recurrent block
#define KH   16          // h-part K-steps (512/32)
#define KSTEPS 24        // fallback: (H_+I_)/32
#define SA   776         // LDS row stride (uniform bank spread, R0-proven)
#define NPAIR (B_ * H_ / 2)
#define G4H  (4 * H_)          // 2048
#define XGSTEP (B_ * G4H)      // 65536 floats per t

typedef __attribute__((ext_vector_type(8))) short short8;
typedef __attribute__((ext_vector_type(4))) float f32x4;

__device__ __forceinline__ unsigned short f2bf_bits(float v) {
    unsigned int u = __builtin_bit_cast(unsigned int, v);
    unsigned int r = (u + 0x7FFFu + ((u >> 16) & 1u)) >> 16;   // RNE
    return (unsigned short)r;
}
__device__ __forceinline__ float sigm(float x) {
    return 1.0f / (1.0f + __expf(-x));
}
__device__ __forceinline__ float tanh_fast(float x) {
    float e = __expf(2.0f * x);          // inf-safe
    return 1.0f - 2.0f / (e + 1.0f);
}

// ws layout: [hbuf: 2*NPAIR u64 = 128KB][Wihb: 4H*I bf16 = 1MB][xg: T*XGSTEP f32 = 512MB]
__global__ void lstm_init(const float* __restrict__ h0,
                          const float* __restrict__ Wih,
                          unsigned long long* __restrict__ ws, int big) {
    int i = blockIdx.x * 256 + threadIdx.x;   // 0..8191
    if (i < NPAIR) {
        const int b = i >> 8;
        const int c = (i & 255) * 2;
        const unsigned lo = f2bf_bits(h0[b * H_ + c]);
        const unsigned hi = f2bf_bits(h0[b * H_ + c + 1]);
        const unsigned pair = lo | (hi << 16);
        ws[i] = ((unsigned long long)pair << 32) | 0u;   // tag 0
        ws[NPAIR + i] = 0xFFFFFFFFull;                   // poison slot 1
    }
    if (big) {
        // convert Wih (4H*I = 524288 f32) to bf16: 8192 threads x 64 elems
        unsigned short* Wihb = (unsigned short*)(ws + 2 * (size_t)NPAIR);
        const int base = i * 64;
#pragma unroll
        for (int k = 0; k < 16; ++k) {
            float4 v = *(const float4*)(Wih + base + k * 4);
            ushort4 p;
            p.x = f2bf_bits(v.x); p.y = f2bf_bits(v.y);
            p.z = f2bf_bits(v.z); p.w = f2bf_bits(v.w);
            *(ushort4*)(Wihb + base + k * 4) = p;
        }
    }
}

// ================= phase 1: xg[t][b][g*H+col] = Wih . x_t =================
__global__ __launch_bounds__(NTHR) void xg_gemm(
    const float* __restrict__ x,          // [B,T,I]
    unsigned long long* __restrict__ ws)
{
    __shared__ __align__(16) unsigned short Axp[B_][I_];   // 16 KB

    const unsigned short* Wihb = (const unsigned short*)(ws + 2 * (size_t)NPAIR);
    float* xg = (float*)(Wihb + (size_t)G4H * I_);

    const int t    = blockIdx.x;
    const int tid  = threadIdx.x;
    const int lane = tid & 63;
    const int wave = tid >> 6;
    const int l15  = lane & 15;
    const int kq8  = (lane >> 4) * 8;

    // stage x_t -> bf16 LDS tile [32][256]
#pragma unroll
    for (int i = 0; i < 4; ++i) {
        const int idx = tid + i * NTHR;
        const int m = idx >> 6, k4 = idx & 63;
        float4 v = *(const float4*)(x + (size_t)m * T_ * I_ +
                                    (size_t)t * I_ + k4 * 4);
        ushort4 pk;
        pk.x = f2bf_bits(v.x); pk.y = f2bf_bits(v.y);
        pk.z = f2bf_bits(v.z); pk.w = f2bf_bits(v.w);
        *(ushort4*)&Axp[m][k4 * 4] = pk;
    }
    __syncthreads();

    // A-fragments (both m-tiles) to regs: 2*8*4 = 64 VGPRs
    short8 afr[2][8];
#pragma unroll
    for (int mt = 0; mt < 2; ++mt)
#pragma unroll
        for (int ks = 0; ks < 8; ++ks)
            afr[mt][ks] = *(const short8*)&Axp[mt * 16 + l15][ks * 32 + kq8];

    // n-tiles: wave w handles n0 = (w + 8j)*16
    for (int j = 0; j < 16; ++j) {
        const int n0 = (wave + 8 * j) * 16;
        short8 bfr[8];
#pragma unroll
        for (int ks = 0; ks < 8; ++ks)
            bfr[ks] = *(const short8*)(Wihb + (size_t)(n0 + l15) * I_ +
                                       ks * 32 + kq8);
        f32x4 a0 = {0.f,0.f,0.f,0.f}, a1 = {0.f,0.f,0.f,0.f};
#pragma unroll
        for (int ks = 0; ks < 8; ++ks) {
            a0 = __builtin_amdgcn_mfma_f32_16x16x32_bf16(afr[0][ks], bfr[ks], a0, 0, 0, 0);
            a1 = __builtin_amdgcn_mfma_f32_16x16x32_bf16(afr[1][ks], bfr[ks], a1, 0, 0, 0);
        }
        // D: row(batch) = (lane>>4)*4+r, col(gate-row) = l15
        float* o = xg + (size_t)t * XGSTEP + n0 + l15;
#pragma unroll
        for (int r = 0; r < 4; ++r) {
            o[(size_t)(((lane >> 4) * 4) + r) * G4H]      = a0[r];
            o[(size_t)(16 + ((lane >> 4) * 4) + r) * G4H] = a1[r];
        }
    }
}

// ================= phase 2: recurrence (x machinery removed) =================
__global__ __launch_bounds__(NTHR, 1) void lstm_rec(
    const float* __restrict__ c0,   // [1,B,H]
    const float* __restrict__ Whh,  // [4H,H]
    const float* __restrict__ bih,  // [4H]
    const float* __restrict__ bhh,  // [4H]
    float* __restrict__ out,        // [B,T,H] ++ h_f ++ c_f
    unsigned long long* ws)
{
    __shared__ __align__(16) unsigned short Als[B_][SA];
    __shared__ float g_ls[B_][4 * JC + 1];

    const unsigned short* Wihb = (const unsigned short*)(ws + 2 * (size_t)NPAIR);
    const float* xg = (const float*)(Wihb + (size_t)G4H * I_);

    const int tid  = threadIdx.x;
    const int bid  = blockIdx.x;
    const int lane = tid & 63;
    const int wave = tid >> 6;
    const int mi   = (wave & 1) * 16;   // batch-tile base
    const int q    = wave >> 1;         // gate index
    const int l15  = lane & 15;
    const int kq8  = (lane >> 4) * 8;

    // persistent B fragments: h-part only (Whh), 16 K-steps = 64 VGPRs
    const int grow = q * H_ + bid * JC + l15;
    short8 bfrag[KH];
#pragma unroll
    for (int s = 0; s < KH; ++s) {
        const int k0 = s * 32 + kq8;
        short8 f;
#pragma unroll
        for (int j = 0; j < 8; ++j)
            f[j] = (short)f2bf_bits(Whh[(size_t)grow * H_ + k0 + j]);
        bfrag[s] = f;
    }

    const int eb   = tid >> 4;
    const int ejj  = tid & 15;
    const int ecol = bid * JC + ejj;
    float bias_i = bih[0 * H_ + ecol] + bhh[0 * H_ + ecol];
    float bias_f = bih[1 * H_ + ecol] + bhh[1 * H_ + ecol];
    float bias_g = bih[2 * H_ + ecol] + bhh[2 * H_ + ecol];
    float bias_o = bih[3 * H_ + ecol] + bhh[3 * H_ + ecol];
    float c_reg  = c0[eb * H_ + ecol];

    // xg(0): stream order guarantees phase 1 is complete
    const float* xp0 = xg + (size_t)eb * G4H + ecol;
    float xg0 = xp0[0], xg1 = xp0[H_], xg2 = xp0[2 * H_], xg3 = xp0[3 * H_];

    for (int t = 0; t < T_; ++t) {
        const unsigned tt = (unsigned)t;
        unsigned long long* hsrc = ws + (size_t)(t & 1) * NPAIR;

        // ---- poll h(t): R0's proven tagged-u64 scheme ----
        unsigned long long hv[16];
        unsigned need = 0xFFFFu;
        do {
#pragma unroll
            for (int i = 0; i < 16; ++i) {
                if (need & (1u << i)) {
                    hv[i] = __hip_atomic_load(&hsrc[tid + i * NTHR],
                                              __ATOMIC_RELAXED,
                                              __HIP_MEMORY_SCOPE_AGENT);
                }
            }
            unsigned ok = 0;
#pragma unroll
            for (int i = 0; i < 16; ++i)
                if ((unsigned)hv[i] == tt) ok |= (1u << i);
            need &= ~ok;
        } while (need);

        // ---- write h pairs to LDS ----
#pragma unroll
        for (int i = 0; i < 16; ++i) {
            const int j = tid + i * NTHR;
            const int m = j >> 8;
            const int c = (j & 255) * 2;
            *(unsigned int*)&Als[m][c] = (unsigned int)(hv[i] >> 32);
        }
        __syncthreads();                              // barrier #1

        // ---- h-GEMM: 16 MFMAs ----
        f32x4 acc = {0.f, 0.f, 0.f, 0.f};
        const int mrow = mi + l15;
#pragma unroll
        for (int s = 0; s < KH; ++s) {
            const short8 a = *(const short8*)&Als[mrow][s * 32 + kq8];
            acc = __builtin_amdgcn_mfma_f32_16x16x32_bf16(a, bfrag[s], acc, 0, 0, 0);
        }
#pragma unroll
        for (int r = 0; r < 4; ++r) {                 // D: col=lane&15, row=(lane>>4)*4+r
            g_ls[mi + (lane >> 4) * 4 + r][q * JC + l15] = acc[r];
        }
        __syncthreads();                              // barrier #2

        // ---- epilogue ----
        const float pi = g_ls[eb][ejj]          + bias_i + xg0;
        const float pf = g_ls[eb][JC + ejj]     + bias_f + xg1;
        const float pg = g_ls[eb][2 * JC + ejj] + bias_g + xg2;
        const float po = g_ls[eb][3 * JC + ejj] + bias_o + xg3;
        const float ig = sigm(pi), fg = sigm(pf);
        const float gg = tanh_fast(pg), og = sigm(po);
        c_reg = fg * c_reg + ig * gg;
        const float h = og * tanh_fast(c_reg);

        // ---- publish h(t+1) ----
        const unsigned hvb = f2bf_bits(h);
        const unsigned nbv = __shfl_xor(hvb, 1);
        if ((ejj & 1) == 0) {
            const unsigned pair = hvb | (nbv << 16);
            const unsigned long long word =
                ((unsigned long long)pair << 32) | (unsigned)(t + 1);
            __hip_atomic_store(
                &ws[(size_t)((t + 1) & 1) * NPAIR + eb * 256 + (ecol >> 1)],
                word, __ATOMIC_RELAXED, __HIP_MEMORY_SCOPE_AGENT);
        }

        // ---- xg(t+1) prefetch (HBM/L2 latency hides under next poll) ----
        if (t + 1 < T_) {
            const float* p = xg + (size_t)(t + 1) * XGSTEP + eb * G4H + ecol;
            xg0 = p[0]; xg1 = p[H_]; xg2 = p[2 * H_]; xg3 = p[3 * H_];
        }

        // ---- deferred HBM stores ----
        out[(size_t)eb * T_ * H_ + (size_t)t * H_ + ecol] = h;
        if (t == T_ - 1) {
            out[(size_t)B_ * T_ * H_ + eb * H_ + ecol] = h;
            out[(size_t)B_ * T_ * H_ + B_ * H_ + eb * H_ + ecol] = c_reg;
        }
    }
}

// ================= fallback: exact R0 kernel (small ws) =================
__global__ __launch_bounds__(NTHR) void lstm_fb(
    const float* __restrict__ x, const float* __restrict__ c0,
    const float* __restrict__ Wih, const float* __restrict__ Whh,
    const float* __restrict__ bih, const float* __restrict__ bhh,
    float* __restrict__ out, unsigned long long* hbuf)
{
    __shared__ __align__(16) unsigned short Als[B_][SA];
    __shared__ float g_ls[B_][4 * JC + 1];

    const int tid  = threadIdx.x;
    const int bid  = blockIdx.x;
    const int lane = tid & 63;
    const int wave = tid >> 6;
    const int mi   = (wave & 1) * 16;
    const int q    = wave >> 1;
    const int l15  = lane & 15;
    const int kq8  = (lane >> 4) * 8;

    const int grow = q * H_ + bid * JC + l15;
    short8 bfrag[KSTEPS];
#pragma unroll
    for (int s = 0; s < KSTEPS; ++s) {
        const int k0 = s * 32 + kq8;
        short8 f;
#pragma unroll
        for (int j = 0; j < 8; ++j) {
            const int k = k0 + j;
            const float v = (k < H_) ? Whh[(size_t)grow * H_ + k]
                                     : Wih[(size_t)grow * I_ + (k - H_)];
            f[j] = (short)f2bf_bits(v);
        }
        bfrag[s] = f;
    }

    const int eb   = tid >> 4;
    const int ejj  = tid & 15;
    const int ecol = bid * JC + ejj;
    float bias_i = bih[0 * H_ + ecol] + bhh[0 * H_ + ecol];
    float bias_f = bih[1 * H_ + ecol] + bhh[1 * H_ + ecol];
    float bias_g = bih[2 * H_ + ecol] + bhh[2 * H_ + ecol];
    float bias_o = bih[3 * H_ + ecol] + bhh[3 * H_ + ecol];
    float c_reg  = c0[eb * H_ + ecol];

    for (int t = 0; t < T_; ++t) {
        float4 xv[4];
#pragma unroll
        for (int i = 0; i < 4; ++i) {
            const int idx = tid + i * NTHR;
            const int m = idx >> 6, k4 = idx & 63;
            xv[i] = *(const float4*)(x + (size_t)m * T_ * I_ +
                                     (size_t)t * I_ + k4 * 4);
        }
        asm volatile("" ::: "memory");

        const unsigned tt = (unsigned)t;
        unsigned long long* hsrc = hbuf + (size_t)(t & 1) * NPAIR;
        unsigned long long hv[16];
        unsigned need = 0xFFFFu;
        do {
#pragma unroll
            for (int i = 0; i < 16; ++i) {
                if (need & (1u << i)) {
                    hv[i] = __hip_atomic_load(&hsrc[tid + i * NTHR],
                                              __ATOMIC_RELAXED,
                                              __HIP_MEMORY_SCOPE_AGENT);
                }
            }
            unsigned ok = 0;
#pragma unroll
            for (int i = 0; i < 16; ++i)
                if ((unsigned)hv[i] == tt) ok |= (1u << i);
            need &= ~ok;
        } while (need);

#pragma unroll
        for (int i = 0; i < 16; ++i) {
            const int j = tid + i * NTHR;
            const int m = j >> 8;
            const int c = (j & 255) * 2;
            *(unsigned int*)&Als[m][c] = (unsigned int)(hv[i] >> 32);
        }
#pragma unroll
        for (int i = 0; i < 4; ++i) {
            const int idx = tid + i * NTHR;
            const int m = idx >> 6, k4 = idx & 63;
            ushort4 p;
            p.x = f2bf_bits(xv[i].x); p.y = f2bf_bits(xv[i].y);
            p.z = f2bf_bits(xv[i].z); p.w = f2bf_bits(xv[i].w);
            *(ushort4*)&Als[m][H_ + k4 * 4] = p;
        }
        __syncthreads();

        f32x4 acc = {0.f, 0.f, 0.f, 0.f};
        const int mrow = mi + l15;
#pragma unroll
        for (int s = 0; s < KSTEPS; ++s) {
            const short8 a = *(const short8*)&Als[mrow][s * 32 + kq8];
            acc = __builtin_amdgcn_mfma_f32_16x16x32_bf16(a, bfrag[s], acc, 0, 0, 0);
        }
#pragma unroll
        for (int r = 0; r < 4; ++r) {
            g_ls[mi + (lane >> 4) * 4 + r][q * JC + l15] = acc[r];
        }
        __syncthreads();

        const float pi = g_ls[eb][ejj]          + bias_i;
        const float pf = g_ls[eb][JC + ejj]     + bias_f;
        const float pg = g_ls[eb][2 * JC + ejj] + bias_g;
        const float po = g_ls[eb][3 * JC + ejj] + bias_o;
        const float ig = sigm(pi), fg = sigm(pf);
        const float gg = tanh_fast(pg), og = sigm(po);
        c_reg = fg * c_reg + ig * gg;
        const float h = og * tanh_fast(c_reg);

        const unsigned hvb = f2bf_bits(h);
        const unsigned nbv = __shfl_xor(hvb, 1);
        if ((ejj & 1) == 0) {
            const unsigned pair = hvb | (nbv << 16);
            const unsigned long long word =
                ((unsigned long long)pair << 32) | (unsigned)(t + 1);
            __hip_atomic_store(
                &hbuf[(size_t)((t + 1) & 1) * NPAIR + eb * 256 + (ecol >> 1)],
                word, __ATOMIC_RELAXED, __HIP_MEMORY_SCOPE_AGENT);
        }

        out[(size_t)eb * T_ * H_ + (size_t)t * H_ + ecol] = h;
        if (t == T_ - 1) {
            out[(size_t)B_ * T_ * H_ + eb * H_ + ecol] = h;
            out[(size_t)B_ * T_ * H_ + B_ * H_ + eb * H_ + ecol] = c_reg;
        }
    }
}

extern "C" void kernel_launch(void* const* d_in, const int* in_sizes, int n_in,
                              void* d_out, int out_size, void* d_ws, size_t ws_size,
                              hipStream_t stream) {
    const float* x   = (const float*)d_in[0];
    const float* h0  = (const float*)d_in[1];
    const float* c0  = (const float*)d_in[2];
    const float* Wih = (const float*)d_in[3];
    const float* Whh = (const float*)d_in[4];
    const float* bih = (const float*)d_in[5];
    const float* bhh = (const float*)d_in[6];
    float* out = (float*)d_out;

    unsigned long long* ws = (unsigned long long*)d_ws;

    const size_t need = 2 * (size_t)NPAIR * 8            // hbuf      128 KB
                      + (size_t)G4H * I_ * 2             // Wihb        1 MB
                      + (size_t)T_ * XGSTEP * 4;         // xg        512 MB
    const int big = (ws_size >= need) ? 1 : 0;

    hipLaunchKernelGGL(lstm_init, dim3(32), dim3(256), 0, stream,
                       h0, Wih, ws, big);
    if (big) {
        hipLaunchKernelGGL(xg_gemm, dim3(T_), dim3(NTHR), 0, stream, x, ws);
        hipLaunchKernelGGL(lstm_rec, dim3(NB), dim3(NTHR), 0, stream,
                           c0, Whh, bih, bhh, out, ws);
    } else {
        hipLaunchKernelGGL(lstm_fb, dim3(NB), dim3(NTHR), 0, stream,
                           x, c0, Wih, Whh, bih, bhh, out, ws);
    }
}